// Round 1
// baseline (3117.185 us; speedup 1.0000x reference)
//
#include <hip/hip_runtime.h>
#include <math.h>

#define NLEVELS 16

struct Cfg {
    float    scale[NLEVELS];
    unsigned res[NLEVELS];
    unsigned offset[NLEVELS];
    unsigned hash_mask;   // bit l set => level l uses hashing
};

__global__ __launch_bounds__(256) void hashenc_kernel(
    const float* __restrict__ in, const float* __restrict__ emb,
    float* __restrict__ out, Cfg cfg, int npts)
{
    int b = blockIdx.x * blockDim.x + threadIdx.x;
    if (b >= npts) return;

    const float x = in[3 * b + 0];
    const float y = in[3 * b + 1];
    const float z = in[3 * b + 2];

    float2* o = reinterpret_cast<float2*>(out) + 16ull * (unsigned long long)b;

    #pragma unroll 1
    for (int l = 0; l < NLEVELS; ++l) {
        const float    s   = cfg.scale[l];
        const unsigned r   = cfg.res[l];
        const unsigned off = cfg.offset[l];
        const bool     use_hash = (cfg.hash_mask >> l) & 1u;

        const float px = x * s + 0.5f;
        const float py = y * s + 0.5f;
        const float pz = z * s + 0.5f;
        const float fxf = floorf(px), fyf = floorf(py), fzf = floorf(pz);
        const float tx = px - fxf, ty = py - fyf, tz = pz - fzf;
        const unsigned gx = (unsigned)fxf, gy = (unsigned)fyf, gz = (unsigned)fzf;
        const unsigned rm1 = r - 1u;

        float a0 = 0.0f, a1 = 0.0f;

        #pragma unroll
        for (int c = 0; c < 8; ++c) {
            const unsigned bx = c & 1u, by = (c >> 1) & 1u, bz = (c >> 2) & 1u;
            const unsigned cx = min(gx + bx, rm1);
            const unsigned cy = min(gy + by, rm1);
            const unsigned cz = min(gz + bz, rm1);
            const float w = (bx ? tx : 1.0f - tx)
                          * (by ? ty : 1.0f - ty)
                          * (bz ? tz : 1.0f - tz);
            unsigned idx;
            if (use_hash) {
                idx = (cx ^ (cy * 2654435761u) ^ (cz * 805459861u)) & 0x7FFFFu;
            } else {
                idx = cx + cy * r + cz * r * r;
            }
            const float2 e = *reinterpret_cast<const float2*>(emb + 2u * (off + idx));
            a0 = fmaf(w, e.x, a0);
            a1 = fmaf(w, e.y, a1);
        }
        o[l] = make_float2(a0, a1);
    }
}

extern "C" void kernel_launch(void* const* d_in, const int* in_sizes, int n_in,
                              void* d_out, int out_size, void* d_ws, size_t ws_size,
                              hipStream_t stream)
{
    const float* in  = (const float*)d_in[0];
    const float* emb = (const float*)d_in[1];
    float* out = (float*)d_out;

    const int npts = in_sizes[0] / 3;

    // Build level config exactly like the numpy reference (float64 math).
    Cfg cfg;
    const double pls_log2 = log2(2048.0 / 16.0) / 15.0;  // log2(per_level_scale)
    const long long max_params = 1ll << 19;
    long long off = 0;
    unsigned hash_mask = 0;
    for (int l = 0; l < NLEVELS; ++l) {
        const double scale = exp2((double)l * pls_log2) * 16.0 - 1.0;
        const int res = (int)ceil(scale) + 1;
        cfg.scale[l]  = (float)scale;
        cfg.res[l]    = (unsigned)res;
        cfg.offset[l] = (unsigned)off;
        long long params = (long long)res * res * res;
        if (params > max_params) {
            params = max_params;
            hash_mask |= (1u << l);
        }
        params = (params + 7) / 8 * 8;
        off += params;
    }
    cfg.hash_mask = hash_mask;

    const int block = 256;
    const int grid = (npts + block - 1) / block;
    hashenc_kernel<<<grid, block, 0, stream>>>(in, emb, out, cfg, npts);
}

// Round 2
// 1605.724 us; speedup vs baseline: 1.9413x; 1.9413x over previous
//
#include <hip/hip_runtime.h>
#include <hip/hip_fp16.h>
#include <math.h>

#define NLEVELS 16
#define TPB 256

struct Cfg {
    float    scale[NLEVELS];
    unsigned res[NLEVELS];
    unsigned offset[NLEVELS];   // entry offsets into table
    unsigned hash_mask;         // bit l => level l hashed (hmap = 2^19)
    int      slot_level[16];    // slot (blockIdx%16) -> level, XCD-pairing
};

// ---- pre-pass: f32 table -> fp16 table in ws (halves gather working set) ----
__global__ __launch_bounds__(TPB) void convert_kernel(
    const float2* __restrict__ emb, __half2* __restrict__ tab, int n)
{
    int i = blockIdx.x * TPB + threadIdx.x;
    if (i < n) {
        float2 e = emb[i];
        tab[i] = __floats2half2_rn(e.x, e.y);
    }
}

// ---- level-partitioned gather. TO_WS: write ws[l][p] (coalesced), else out[p][l] ----
template <bool TO_WS>
__global__ __launch_bounds__(TPB) void gather_kernel(
    const float* __restrict__ in, const __half2* __restrict__ tab,
    float2* __restrict__ dst, Cfg cfg, int npts)
{
    const int slot  = blockIdx.x & 15;
    const int chunk = blockIdx.x >> 4;
    const int l     = cfg.slot_level[slot];
    const int p     = chunk * TPB + threadIdx.x;
    if (p >= npts) return;

    const float x = in[3 * p + 0];
    const float y = in[3 * p + 1];
    const float z = in[3 * p + 2];

    const float    s   = cfg.scale[l];
    const unsigned r   = cfg.res[l];
    const unsigned off = cfg.offset[l];
    const bool use_hash = (cfg.hash_mask >> l) & 1u;

    const float px = x * s + 0.5f;
    const float py = y * s + 0.5f;
    const float pz = z * s + 0.5f;
    const float fxf = floorf(px), fyf = floorf(py), fzf = floorf(pz);
    const float tx = px - fxf, ty = py - fyf, tz = pz - fzf;
    const unsigned gx = (unsigned)fxf, gy = (unsigned)fyf, gz = (unsigned)fzf;
    const unsigned rm1 = r - 1u;

    float a0 = 0.0f, a1 = 0.0f;

    #pragma unroll
    for (int c = 0; c < 8; ++c) {
        const unsigned bx = c & 1u, by = (c >> 1) & 1u, bz = (c >> 2) & 1u;
        const unsigned cx = min(gx + bx, rm1);
        const unsigned cy = min(gy + by, rm1);
        const unsigned cz = min(gz + bz, rm1);
        const float w = (bx ? tx : 1.0f - tx)
                      * (by ? ty : 1.0f - ty)
                      * (bz ? tz : 1.0f - tz);
        unsigned idx;
        if (use_hash) {
            idx = (cx ^ (cy * 2654435761u) ^ (cz * 805459861u)) & 0x7FFFFu;
        } else {
            idx = cx + cy * r + cz * r * r;
        }
        const float2 e = __half22float2(tab[off + idx]);
        a0 = fmaf(w, e.x, a0);
        a1 = fmaf(w, e.y, a1);
    }

    if (TO_WS) {
        dst[(size_t)l * npts + p] = make_float2(a0, a1);       // coalesced
    } else {
        dst[(size_t)p * NLEVELS + l] = make_float2(a0, a1);    // strided fallback
    }
}

// ---- ws[L][B] float2 -> out[B][L*2], full-128B-line stores per thread ----
__global__ __launch_bounds__(TPB) void transpose_kernel(
    const float2* __restrict__ ws, float4* __restrict__ out, int npts)
{
    int p = blockIdx.x * TPB + threadIdx.x;
    if (p >= npts) return;
    float2 v[NLEVELS];
    #pragma unroll
    for (int l = 0; l < NLEVELS; ++l) v[l] = ws[(size_t)l * npts + p];
    float4* o = out + (size_t)p * 8;
    #pragma unroll
    for (int i = 0; i < 8; ++i)
        o[i] = make_float4(v[2*i].x, v[2*i].y, v[2*i+1].x, v[2*i+1].y);
}

// ---- monolithic f32 fallback (round-1 kernel) if ws is too small ----
__global__ __launch_bounds__(TPB) void hashenc_mono_kernel(
    const float* __restrict__ in, const float* __restrict__ emb,
    float* __restrict__ out, Cfg cfg, int npts)
{
    int b = blockIdx.x * TPB + threadIdx.x;
    if (b >= npts) return;
    const float x = in[3*b], y = in[3*b+1], z = in[3*b+2];
    float2* o = reinterpret_cast<float2*>(out) + (size_t)NLEVELS * b;
    #pragma unroll 1
    for (int l = 0; l < NLEVELS; ++l) {
        const float s = cfg.scale[l];
        const unsigned r = cfg.res[l], off = cfg.offset[l];
        const bool use_hash = (cfg.hash_mask >> l) & 1u;
        const float px = x*s+0.5f, py = y*s+0.5f, pz = z*s+0.5f;
        const float fxf = floorf(px), fyf = floorf(py), fzf = floorf(pz);
        const float tx = px-fxf, ty = py-fyf, tz = pz-fzf;
        const unsigned gx = (unsigned)fxf, gy = (unsigned)fyf, gz = (unsigned)fzf;
        const unsigned rm1 = r - 1u;
        float a0 = 0.f, a1 = 0.f;
        #pragma unroll
        for (int c = 0; c < 8; ++c) {
            const unsigned bx = c&1u, by = (c>>1)&1u, bz = (c>>2)&1u;
            const unsigned cx = min(gx+bx, rm1), cy = min(gy+by, rm1), cz = min(gz+bz, rm1);
            const float w = (bx?tx:1.f-tx)*(by?ty:1.f-ty)*(bz?tz:1.f-tz);
            unsigned idx = use_hash ? ((cx ^ (cy*2654435761u) ^ (cz*805459861u)) & 0x7FFFFu)
                                    : (cx + cy*r + cz*r*r);
            const float2 e = *reinterpret_cast<const float2*>(emb + 2u*(off+idx));
            a0 = fmaf(w, e.x, a0); a1 = fmaf(w, e.y, a1);
        }
        o[l] = make_float2(a0, a1);
    }
}

extern "C" void kernel_launch(void* const* d_in, const int* in_sizes, int n_in,
                              void* d_out, int out_size, void* d_ws, size_t ws_size,
                              hipStream_t stream)
{
    const float* in  = (const float*)d_in[0];
    const float* emb = (const float*)d_in[1];
    float* out = (float*)d_out;
    const int npts = in_sizes[0] / 3;

    // Build level config exactly like the numpy reference (float64 math).
    Cfg cfg;
    const double pls_log2 = log2(2048.0 / 16.0) / 15.0;
    const long long max_params = 1ll << 19;
    long long off = 0;
    unsigned hash_mask = 0;
    for (int l = 0; l < NLEVELS; ++l) {
        const double scale = exp2((double)l * pls_log2) * 16.0 - 1.0;
        const int res = (int)ceil(scale) + 1;
        cfg.scale[l]  = (float)scale;
        cfg.res[l]    = (unsigned)res;
        cfg.offset[l] = (unsigned)off;
        long long params = (long long)res * res * res;
        if (params > max_params) { params = max_params; hash_mask |= (1u << l); }
        params = (params + 7) / 8 * 8;
        off += params;
    }
    cfg.hash_mask = hash_mask;
    const long long total_entries = off;  // 6098120

    // slot (blockIdx%16) -> level. XCD k gets slots {k, k+8} (round-robin
    // heuristic). Pair small dense levels with 2MB hash levels:
    //   XCD0:{0,5} XCD1:{1,6} XCD2:{2,7} XCD3:{3,8} XCD4:{4,9}
    //   XCD5:{10,11} XCD6:{12,13} XCD7:{14,15}
    const int slot_level[16] = {0,1,2,3,4,10,12,14, 5,6,7,8,9,11,13,15};
    for (int i = 0; i < 16; ++i) cfg.slot_level[i] = slot_level[i];

    const size_t tab_bytes  = (size_t)total_entries * 4;           // half2/entry
    const size_t tab_pad    = (tab_bytes + 255) & ~(size_t)255;
    const size_t tr_bytes   = (size_t)NLEVELS * npts * 8;          // float2 staging

    const int chunks = (npts + TPB - 1) / TPB;

    if (ws_size >= tab_pad + tr_bytes) {
        __half2* tab = (__half2*)d_ws;
        float2*  wst = (float2*)((char*)d_ws + tab_pad);
        convert_kernel<<<(int)((total_entries + TPB - 1) / TPB), TPB, 0, stream>>>(
            (const float2*)emb, tab, (int)total_entries);
        gather_kernel<true><<<chunks * 16, TPB, 0, stream>>>(in, tab, wst, cfg, npts);
        transpose_kernel<<<chunks, TPB, 0, stream>>>(wst, (float4*)out, npts);
    } else if (ws_size >= tab_bytes) {
        __half2* tab = (__half2*)d_ws;
        convert_kernel<<<(int)((total_entries + TPB - 1) / TPB), TPB, 0, stream>>>(
            (const float2*)emb, tab, (int)total_entries);
        gather_kernel<false><<<chunks * 16, TPB, 0, stream>>>(in, tab, (float2*)out, cfg, npts);
    } else {
        hashenc_mono_kernel<<<chunks, TPB, 0, stream>>>(in, emb, out, cfg, npts);
    }
}